// Round 6
// baseline (1002.768 us; speedup 1.0000x reference)
//
#include <hip/hip_runtime.h>
#include <hip/hip_bf16.h>
#include <stdint.h>

typedef __hip_bfloat16 bf16;
typedef float f32x4 __attribute__((ext_vector_type(4)));
typedef short s16x8 __attribute__((ext_vector_type(8)));
typedef short s16x4 __attribute__((ext_vector_type(4)));

#define DEV __device__ __forceinline__

static constexpr int S_ = 2048, H_ = 1024, D_ = 512, I_ = 4096, V_ = 32000;
static constexpr int SLn = 32, Lc = 2;
static constexpr size_t LOGITS_N = (size_t)S_ * V_;

DEV float gelu_f(float x) {
    float x3 = x * x * x;
    return 0.5f * x * (1.f + tanhf(0.7978845608028654f * (x + 0.044715f * x3)));
}

#define AS1(p) ((const __attribute__((address_space(1))) void*)(uintptr_t)(p))
#define AS3(p) ((__attribute__((address_space(3))) void*)(uint32_t)(uintptr_t)(p))

// ======================= unified pipelined GEMM (NT) ========================
// C[M,N] = A[M,K](lda) @ BT[N,K](ldb=K)^T. BK=32, 3 LDS slots, 2-ahead
// prefetch, counted vmcnt once per K-tile (never 0 mid-loop). Slots sized so
// >=2 blocks/CU co-reside: cross-block TLP covers barriers + the C-write tail
// (R5 lesson: 1 block/CU serializes epilogue writes with compute).
// XOR-subtile LDS swizzle (0-conflict, verified R3-R5), XCD-chunked m-fastest
// block swizzle, setprio around MFMA cluster.
// FLAGS: 1=bias, 2=gelu, 4=store f32, 8=store bf16
template <int BM, int BN, int TH, int WM, int WN, int MINW, int FLAGS>
__global__ __launch_bounds__(TH, MINW) void gemm_p6(
    const bf16* __restrict__ A, int lda, const bf16* __restrict__ BT,
    const float* __restrict__ bias, float* __restrict__ Cf, int ldf,
    bf16* __restrict__ Cb, int ldb2, int K, int Mt, int Nt) {
    constexpr int FM = BM / (WM * 16), FN = BN / (WN * 16);
    constexpr int CA = (BM * 4) / TH, CB = (BN * 4) / TH, CH = CA + CB;
    constexpr int NPH = (FM * FN >= 32) ? 2 : 1;  // phases per K-tile
    constexpr int FMP = FM / NPH;
    constexpr int SLOT = (BM + BN) * 32;  // shorts per slot
    __shared__ short lds[3 * SLOT];
    const int tid = threadIdx.x, lane = tid & 63;
    const int wm = (tid >> 6) / WN, wn = (tid >> 6) % WN;

    int nwg = Mt * Nt;
    int bid = blockIdx.x, wgid = bid;
    if ((nwg & 7) == 0) {  // bijective XCD chunking
        int cpx = nwg >> 3;
        wgid = (bid & 7) * cpx + (bid >> 3);
    }
    const int m0 = (wgid % Mt) * BM, n0 = (wgid / Mt) * BN;

    // per-lane global sources, inverse-swizzled so linear gload_lds dest +
    // swizzled ds_read line up (both-sides rule).
    const bf16* aS[CA];
    const bf16* bS[CB];
#pragma unroll
    for (int c = 0; c < CA; ++c) {
        int L = (c * TH + tid) * 16;
        int sidx = L >> 10, w = L & 1023;
        int r16 = w >> 6;
        int c2 = (w & 63) ^ (((r16 >> 3) & 1) << 5);
        aS[c] = A + (size_t)(m0 + sidx * 16 + r16) * lda + (c2 >> 1);
    }
#pragma unroll
    for (int c = 0; c < CB; ++c) {
        int L = (c * TH + tid) * 16;
        int sidx = L >> 10, w = L & 1023;
        int r16 = w >> 6;
        int c2 = (w & 63) ^ (((r16 >> 3) & 1) << 5);
        bS[c] = BT + (size_t)(n0 + sidx * 16 + r16) * K + (c2 >> 1);
    }

    auto stageA = [&](int kt, int slot) {
        short* dst = &lds[slot * SLOT];
#pragma unroll
        for (int c = 0; c < CA; ++c)
            __builtin_amdgcn_global_load_lds(AS1(aS[c] + kt * 32), AS3(dst + (c * TH + tid) * 8), 16, 0, 0);
    };
    auto stageB = [&](int kt, int slot) {
        short* dst = &lds[slot * SLOT + BM * 32];
#pragma unroll
        for (int c = 0; c < CB; ++c)
            __builtin_amdgcn_global_load_lds(AS1(bS[c] + kt * 32), AS3(dst + (c * TH + tid) * 8), 16, 0, 0);
    };

    // swizzled per-lane ds_read offset (shorts) — verified 0-conflict
    const int laneoff = ((lane & 15) * 64 + ((((lane >> 4) * 8) ^ (((lane >> 3) & 1) << 4)) << 1)) >> 1;

    f32x4 acc[FM][FN];
#pragma unroll
    for (int i = 0; i < FM; i++)
#pragma unroll
        for (int j = 0; j < FN; j++)
#pragma unroll
            for (int r = 0; r < 4; r++) acc[i][j][r] = 0.f;

    const int NT = K >> 5;
    stageA(0, 0); stageB(0, 0);
    stageA(1, 1); stageB(1, 1);
    asm volatile("s_waitcnt vmcnt(%0)" ::"n"(CH) : "memory");  // tile 0 landed
    __builtin_amdgcn_s_barrier();

    int sl = 0, ss = 2;  // slot of tile t, slot for tile t+2
    for (int t = 0; t < NT; ++t) {
        const short* as = &lds[sl * SLOT];
        const short* bs = as + BM * 32;
        s16x8 bf[FN];
#pragma unroll
        for (int p = 0; p < NPH; ++p) {
            // ds_read this phase's operands (latency drains in barrier wait)
            s16x8 af[FMP];
#pragma unroll
            for (int i = 0; i < FMP; i++)
                af[i] = *(const s16x8*)&as[(wm * FM + p * FMP + i) * 512 + laneoff];
            if (p == 0) {
#pragma unroll
                for (int j = 0; j < FN; j++)
                    bf[j] = *(const s16x8*)&bs[(wn * FN + j) * 512 + laneoff];
            }
            // stage tile t+2 into the slot freed at tile t-1
            if (t + 2 < NT) {
                if (NPH == 1) {
                    stageA(t + 2, ss);
                    stageB(t + 2, ss);
                } else if (p == 0) {
                    stageA(t + 2, ss);
                } else {
                    stageB(t + 2, ss);
                }
            }
            // tile-boundary counted vmcnt: t+1 landed; t+2 stays in flight
            if (p == NPH - 1) {
                if (t + 2 < NT)
                    asm volatile("s_waitcnt vmcnt(%0)" ::"n"(CH) : "memory");
                else if (t + 1 < NT)
                    asm volatile("s_waitcnt vmcnt(0)" ::: "memory");
            }
            __builtin_amdgcn_s_barrier();
            __builtin_amdgcn_sched_barrier(0);  // pin MFMA cluster below barrier
            __builtin_amdgcn_s_setprio(1);
#pragma unroll
            for (int i = 0; i < FMP; i++)
#pragma unroll
                for (int j = 0; j < FN; j++)
                    acc[p * FMP + i][j] =
                        __builtin_amdgcn_mfma_f32_16x16x32_bf16(af[i], bf[j], acc[p * FMP + i][j], 0, 0, 0);
            __builtin_amdgcn_s_setprio(0);
            __builtin_amdgcn_s_barrier();
        }
        sl = (sl == 2) ? 0 : sl + 1;
        ss = (ss == 2) ? 0 : ss + 1;
    }

#pragma unroll
    for (int i = 0; i < FM; i++) {
        int gr0 = m0 + (wm * FM + i) * 16 + ((lane >> 4) << 2);
#pragma unroll
        for (int j = 0; j < FN; j++) {
            int gc = n0 + (wn * FN + j) * 16 + (lane & 15);
            float bv = (FLAGS & 1) ? bias[gc] : 0.f;
#pragma unroll
            for (int r = 0; r < 4; r++) {
                float v = acc[i][j][r] + bv;
                if (FLAGS & 2) v = gelu_f(v);
                if (FLAGS & 4) Cf[(size_t)(gr0 + r) * ldf + gc] = v;
                if (FLAGS & 8) Cb[(size_t)(gr0 + r) * ldb2 + gc] = __float2bfloat16(v);
            }
        }
    }
}

// ------------------------ transpose f32 -> bf16^T ---------------------------
__global__ __launch_bounds__(256) void transpose_bf16_kernel(const float* __restrict__ W,
                                                             bf16* __restrict__ WT, int K, int N) {
    __shared__ float t[32][33];
    int tx = threadIdx.x & 31, ty = threadIdx.x >> 5;
    int kb = blockIdx.y * 32, nb = blockIdx.x * 32;
#pragma unroll
    for (int i = 0; i < 4; i++)
        t[ty + 8 * i][tx] = W[(size_t)(kb + ty + 8 * i) * N + nb + tx];
    __syncthreads();
#pragma unroll
    for (int i = 0; i < 4; i++)
        WT[(size_t)(nb + ty + 8 * i) * K + kb + tx] = __float2bfloat16(t[tx][ty + 8 * i]);
}

// ------------------------------ f32 -> bf16 ---------------------------------
__global__ void conv_bf16_kernel(const float* __restrict__ src, bf16* __restrict__ dst) {
    size_t i = (size_t)blockIdx.x * 256 + threadIdx.x;
    f32x4 v = ((const f32x4*)src)[i];
    s16x4 o;
#pragma unroll
    for (int j = 0; j < 4; j++) {
        bf16 h = __float2bfloat16(v[j]);
        o[j] = *(short*)&h;
    }
    ((s16x4*)dst)[i] = o;
}

// ------------------------------ embedding ----------------------------------
__global__ void embed_kernel(const int* __restrict__ ids, const float* __restrict__ emb,
                             const float* __restrict__ pos, float* __restrict__ hF,
                             bf16* __restrict__ hB) {
    int t = blockIdx.x, tid = threadIdx.x;
    int id = ids[t];
    f32x4 v = ((const f32x4*)(emb + (size_t)id * H_))[tid];
    f32x4 q = ((const f32x4*)(pos + (size_t)t * H_))[tid];
    v = v + q;
    ((f32x4*)(hF + (size_t)t * H_))[tid] = v;
    s16x4 o;
#pragma unroll
    for (int j = 0; j < 4; j++) {
        bf16 h = __float2bfloat16(v[j]);
        o[j] = *(short*)&h;
    }
    ((s16x4*)(hB + (size_t)t * 1536))[tid] = o;  // strided into hrB
}

// ------------------------------ LayerNorm ----------------------------------
__global__ __launch_bounds__(256) void ln_kernel(const float* __restrict__ x,
                                                 const float* __restrict__ res,
                                                 const float* __restrict__ g,
                                                 const float* __restrict__ b,
                                                 float* __restrict__ of, bf16* __restrict__ ob,
                                                 int ldo) {
    __shared__ float red[8];
    int row = blockIdx.x, tid = threadIdx.x, lane = tid & 63, wid = tid >> 6;
    const float* xr = x + (size_t)row * H_;
    float v[4];
#pragma unroll
    for (int j = 0; j < 4; j++) {
        int c = tid + 256 * j;
        v[j] = xr[c] + (res ? res[(size_t)row * H_ + c] : 0.f);
    }
    float s = v[0] + v[1] + v[2] + v[3];
#pragma unroll
    for (int o = 32; o; o >>= 1) s += __shfl_xor(s, o);
    if (!lane) red[wid] = s;
    __syncthreads();
    float mean = (red[0] + red[1] + red[2] + red[3]) * (1.f / H_);
    float q = 0.f;
#pragma unroll
    for (int j = 0; j < 4; j++) {
        float d = v[j] - mean;
        q += d * d;
    }
#pragma unroll
    for (int o = 32; o; o >>= 1) q += __shfl_xor(q, o);
    if (!lane) red[4 + wid] = q;
    __syncthreads();
    float var = (red[4] + red[5] + red[6] + red[7]) * (1.f / H_);
    float rstd = rsqrtf(var + 1e-5f);
#pragma unroll
    for (int j = 0; j < 4; j++) {
        int c = tid + 256 * j;
        float o2 = (v[j] - mean) * rstd * g[c] + b[c];
        if (of) of[(size_t)row * H_ + c] = o2;
        if (ob) ob[(size_t)row * ldo + c] = __float2bfloat16(o2);
    }
}

// --------------------- mem transpose for attn scores ------------------------
__global__ void memt_kernel(const float* __restrict__ fast0, const float* __restrict__ slow0,
                            float* __restrict__ memT) {
    int idx = blockIdx.x * 256 + threadIdx.x;
    int d = idx >> 6, n = idx & 63;
    const float* m = (n < 32) ? fast0 + (size_t)n * D_ : slow0 + (size_t)(n - 32) * D_;
    memT[idx] = m[d];
}

// ---------------- attention (fused keynorm), 1 q-row per wave ---------------
__global__ __launch_bounds__(256) void attn_kernel(const float* __restrict__ keys,
                                                   const float* __restrict__ memT,
                                                   const float* __restrict__ fast0,
                                                   const float* __restrict__ slow0,
                                                   bf16* __restrict__ qr, bf16* __restrict__ hr) {
    __shared__ float klds[4][512];
    int wid = threadIdx.x >> 6, lane = threadIdx.x & 63;
    int r = blockIdx.x * 4 + wid;
    float kv[8], ss = 0.f;
#pragma unroll
    for (int j = 0; j < 8; j++) {
        kv[j] = keys[(size_t)r * D_ + lane + 64 * j];
        ss += kv[j] * kv[j];
    }
#pragma unroll
    for (int o = 32; o; o >>= 1) ss += __shfl_xor(ss, o);
    float inv = 1.f / (sqrtf(ss) + 1e-6f);
#pragma unroll
    for (int j = 0; j < 8; j++) {
        kv[j] *= inv;
        klds[wid][lane + 64 * j] = kv[j];
    }
    __syncthreads();
    float s0 = 0.f, s1 = 0.f, s2 = 0.f, s3 = 0.f;
#pragma unroll 8
    for (int d = 0; d < 512; d += 4) {
        s0 = fmaf(klds[wid][d + 0], memT[(d + 0) * 64 + lane], s0);
        s1 = fmaf(klds[wid][d + 1], memT[(d + 1) * 64 + lane], s1);
        s2 = fmaf(klds[wid][d + 2], memT[(d + 2) * 64 + lane], s2);
        s3 = fmaf(klds[wid][d + 3], memT[(d + 3) * 64 + lane], s3);
    }
    float s = (s0 + s1 + s2 + s3) * 0.044194173824159216f;
    float m = s;
#pragma unroll
    for (int o = 32; o; o >>= 1) m = fmaxf(m, __shfl_xor(m, o));
    float p = expf(s - m);
    float sum = p;
#pragma unroll
    for (int o = 32; o; o >>= 1) sum += __shfl_xor(sum, o);
    float pn = p / sum;
    float rv[8];
#pragma unroll
    for (int j = 0; j < 8; j++) rv[j] = 0.f;
    for (int n2 = 0; n2 < 64; ++n2) {
        float a2 = __shfl(pn, n2);
        const float* m2 = (n2 < 32) ? (fast0 + (size_t)n2 * D_) : (slow0 + (size_t)(n2 - 32) * D_);
#pragma unroll
        for (int j = 0; j < 8; j++) rv[j] = fmaf(a2, m2[lane + 64 * j], rv[j]);
    }
#pragma unroll
    for (int j = 0; j < 8; j++) {
        bf16 o = __float2bfloat16(rv[j] * kv[j]);
        qr[(size_t)r * 1536 + 1024 + lane + 64 * j] = o;
        hr[(size_t)r * 1536 + 1024 + lane + 64 * j] = o;
    }
}

// ------------------------- scan coefficients --------------------------------
__global__ void coef_kernel(float* __restrict__ coef) {
    int t = blockIdx.x * 256 + threadIdx.x;
    int j0 = (t + 9) / 10;
    float a = powf(0.9f, (float)(2047 - t + 205 - j0));
    float b = 0.f;
    for (int j = j0; j < 205; ++j)
        b += powf(0.9f, (float)(10 * j - t + j - j0)) * powf(0.99f, (float)(204 - j));
    b *= 0.1f;
    coef[t] = a;
    coef[2048 + t] = b;
    if (t == 0) {
        coef[4096] = powf(0.99f, 205.f);
        float cfs = 0.f;
        for (int j = 0; j < 205; ++j)
            cfs += powf(0.9f, (float)(11 * j + 1)) * powf(0.99f, (float)(204 - j));
        coef[4097] = 0.1f * cfs;
    }
}

// -------------------- gates epilogue: sigmoid * coef ------------------------
__global__ void sigcoef_kernel(const float* __restrict__ raw, const float* __restrict__ coef,
                               float* __restrict__ ga, float* __restrict__ gb) {
    int i = blockIdx.x * 256 + threadIdx.x;  // 2048*32
    int r = i >> 5, n = i & 31;
    float g = 1.f / (1.f + expf(-raw[r * 64 + n]));
    ga[i] = g * coef[r];
    gb[i] = g * coef[2048 + r];
}

// ------------------------- scan: split-T partial GEMMs ----------------------
__global__ __launch_bounds__(256) void scan_part_kernel(const float* __restrict__ items,
                                                        const float* __restrict__ ga,
                                                        const float* __restrict__ gb,
                                                        float* __restrict__ pF,
                                                        float* __restrict__ pS) {
    int tid = threadIdx.x;
    int d = (blockIdx.x & 7) * 64 + (tid & 63);
    int mg = (blockIdx.x >> 3) & 1;
    int tc = blockIdx.x >> 4;
    int m0 = mg * 16 + (tid >> 6) * 4;
    float aF[4] = {0.f, 0.f, 0.f, 0.f}, aS[4] = {0.f, 0.f, 0.f, 0.f};
    for (int t = tc * 128; t < tc * 128 + 128; ++t) {
        float it = items[(size_t)t * D_ + d];
#pragma unroll
        for (int j = 0; j < 4; j++) {
            aF[j] = fmaf(ga[t * 32 + m0 + j], it, aF[j]);
            aS[j] = fmaf(gb[t * 32 + m0 + j], it, aS[j]);
        }
    }
#pragma unroll
    for (int j = 0; j < 4; j++) {
        pF[((size_t)tc * 32 + m0 + j) * D_ + d] = aF[j];
        pS[((size_t)tc * 32 + m0 + j) * D_ + d] = aS[j];
    }
}

__global__ __launch_bounds__(256) void scan_reduce_kernel(const float* __restrict__ pF,
                                                          const float* __restrict__ pS,
                                                          const float* __restrict__ coef,
                                                          const float* __restrict__ fast0,
                                                          const float* __restrict__ slow0,
                                                          float* __restrict__ fastO,
                                                          float* __restrict__ slowO) {
    int i = blockIdx.x * 256 + threadIdx.x;  // 16384
    float f = 0.f, s = 0.f;
#pragma unroll
    for (int c = 0; c < 16; c++) {
        f += pF[(size_t)c * 32 * D_ + i];
        s += pS[(size_t)c * 32 * D_ + i];
    }
    fastO[i] = f;
    slowO[i] = s + coef[4096] * slow0[i] + coef[4097] * fast0[i];
}

// ------------------------------- host side ----------------------------------
static inline void gemmM(hipStream_t st, const bf16* A, int lda, const bf16* BT,
                         const float* bias, float* Cf, int ldf, bf16* Cb, int ldb2,
                         int M, int N, int K, int flags) {
    int Mt = M / 128, Nt = N / 64;
    dim3 g(Mt * Nt), b(256);
#define GCASE(fl)                                                                              \
    if (flags == fl) {                                                                         \
        gemm_p6<128, 64, 256, 2, 2, 4, fl><<<g, b, 0, st>>>(A, lda, BT, bias, Cf, ldf, Cb,     \
                                                            ldb2, K, Mt, Nt);                  \
        return;                                                                                \
    }
    GCASE(13)
    GCASE(9)
    GCASE(11)
    GCASE(5)
#undef GCASE
}

static inline void transp(hipStream_t st, const float* W, bf16* WT, int K, int N) {
    transpose_bf16_kernel<<<dim3(N / 32, K / 32), 256, 0, st>>>(W, WT, K, N);
}

extern "C" void kernel_launch(void* const* d_in, const int* in_sizes, int n_in,
                              void* d_out, int out_size, void* d_ws, size_t ws_size,
                              hipStream_t stream) {
    const int* ids = (const int*)d_in[0];
    const float* fastS = (const float*)d_in[1];
    const float* slowS = (const float*)d_in[2];
    const float* emb = (const float*)d_in[3];
    const float* pos = (const float*)d_in[4];
    const float* W_item = (const float*)d_in[5];
    const float* b_item = (const float*)d_in[6];
    const float* W_q = (const float*)d_in[7];
    const float* b_q = (const float*)d_in[8];
    const float* rh_W1 = (const float*)d_in[9];
    const float* rh_b1 = (const float*)d_in[10];
    const float* rh_W2 = (const float*)d_in[11];
    const float* rh_b2 = (const float*)d_in[12];
    const float* gate_W = (const float*)d_in[13];
    const float* gate_b = (const float*)d_in[14];
    const float* W_out = (const float*)d_in[15];
    const float* b_out = (const float*)d_in[16];
    const float* ln1_g = (const float*)d_in[17];
    const float* ln1_b = (const float*)d_in[18];
    const float* ffn_W1 = (const float*)d_in[19];
    const float* ffn_b1 = (const float*)d_in[20];
    const float* ffn_W2 = (const float*)d_in[21];
    const float* ffn_b2 = (const float*)d_in[22];
    const float* ln2_g = (const float*)d_in[23];
    const float* ln2_b = (const float*)d_in[24];
    const float* fln_g = (const float*)d_in[25];
    const float* fln_b = (const float*)d_in[26];
    float* outP = (float*)d_out;

    size_t off = 0;
    char* base = (char*)d_ws;
    auto alloc = [&](size_t n) -> char* {
        char* p = base + off;
        off += (n + 255) & ~(size_t)255;
        return p;
    };
    bf16* wItemT = (bf16*)alloc((size_t)Lc * D_ * H_ * 2);
    bf16* wQT = (bf16*)alloc((size_t)Lc * H_ * H_ * 2);
    bf16* rh1T = (bf16*)alloc((size_t)Lc * (2 * D_) * D_ * 2);
    bf16* rh2T = (bf16*)alloc((size_t)Lc * D_ * (2 * D_) * 2);
    bf16* wOutT = (bf16*)alloc((size_t)Lc * H_ * 1536 * 2);
    bf16* f1T = (bf16*)alloc((size_t)Lc * I_ * H_ * 2);
    bf16* f2T = (bf16*)alloc((size_t)Lc * H_ * I_ * 2);
    bf16* gWT = (bf16*)alloc((size_t)Lc * 64 * 1536 * 2);
    bf16* embB = (bf16*)alloc((size_t)V_ * H_ * 2);
    float* hF = (float*)alloc((size_t)S_ * H_ * 4);
    bf16* hrB = (bf16*)alloc((size_t)S_ * 1536 * 2);  // [h | retrieved]
    bf16* hB = hrB;                                   // h part, ld=1536
    float* itemsF = (float*)alloc((size_t)S_ * D_ * 4);
    bf16* itemsB = (bf16*)alloc((size_t)S_ * D_ * 2);
    bf16* qrB = (bf16*)alloc((size_t)S_ * 1536 * 2);  // [query | retrieved]
    bf16* k1B = (bf16*)alloc((size_t)S_ * (2 * D_) * 2);
    float* keysF = (float*)alloc((size_t)S_ * D_ * 4);
    float* outF = (float*)alloc((size_t)S_ * H_ * 4);
    bf16* ffn1B = (bf16*)alloc((size_t)S_ * I_ * 2);
    float* gRawF = (float*)alloc((size_t)S_ * 64 * 4);
    float* gaF = (float*)alloc((size_t)S_ * SLn * 4);
    float* gbF = (float*)alloc((size_t)S_ * SLn * 4);
    float* coefF = (float*)alloc(4200 * 4);
    float* memT = (float*)alloc((size_t)D_ * 64 * 4);
    float* pF = (float*)alloc((size_t)16 * SLn * D_ * 4);
    float* pS = (float*)alloc((size_t)16 * SLn * D_ * 4);

    coef_kernel<<<8, 256, 0, stream>>>(coefF);
    for (int l = 0; l < Lc; ++l) {
        transp(stream, W_item + (size_t)l * H_ * D_, wItemT + (size_t)l * D_ * H_, H_, D_);
        transp(stream, W_q + (size_t)l * H_ * H_, wQT + (size_t)l * H_ * H_, H_, H_);
        transp(stream, rh_W1 + (size_t)l * D_ * 2 * D_, rh1T + (size_t)l * 2 * D_ * D_, D_, 2 * D_);
        transp(stream, rh_W2 + (size_t)l * 2 * D_ * D_, rh2T + (size_t)l * D_ * 2 * D_, 2 * D_, D_);
        transp(stream, W_out + (size_t)l * 1536 * H_, wOutT + (size_t)l * H_ * 1536, 1536, H_);
        transp(stream, ffn_W1 + (size_t)l * H_ * I_, f1T + (size_t)l * I_ * H_, H_, I_);
        transp(stream, ffn_W2 + (size_t)l * I_ * H_, f2T + (size_t)l * H_ * I_, I_, H_);
        transp(stream, gate_W + (size_t)l * 1536 * 64, gWT + (size_t)l * 64 * 1536, 1536, 64);
    }
    conv_bf16_kernel<<<(int)((size_t)V_ * H_ / 4 / 256), 256, 0, stream>>>(emb, embB);
    embed_kernel<<<S_, 256, 0, stream>>>(ids, emb, pos, hF, hB);

    for (int l = 0; l < Lc; ++l) {
        const float* fast0 = fastS + (size_t)l * SLn * D_;
        const float* slow0 = slowS + (size_t)l * SLn * D_;
        gemmM(stream, hB, 1536, wItemT + (size_t)l * D_ * H_, b_item + l * D_, itemsF, D_,
              itemsB, D_, S_, D_, H_, 13);
        gemmM(stream, hB, 1536, wQT + (size_t)l * H_ * H_, b_q + l * H_, nullptr, 0, qrB, 1536,
              S_, H_, H_, 9);
        gemmM(stream, itemsB, D_, rh1T + (size_t)l * 2 * D_ * D_, rh_b1 + l * 2 * D_, nullptr, 0,
              k1B, 2 * D_, S_, 2 * D_, D_, 11);
        gemmM(stream, k1B, 2 * D_, rh2T + (size_t)l * D_ * 2 * D_, rh_b2 + l * D_, keysF, D_,
              nullptr, 0, S_, D_, 2 * D_, 5);
        memt_kernel<<<128, 256, 0, stream>>>(fast0, slow0, memT);
        attn_kernel<<<S_ / 4, 256, 0, stream>>>(keysF, memT, fast0, slow0, qrB, hrB);
        gemmM(stream, hrB, 1536, gWT + (size_t)l * 64 * 1536, gate_b + l * 64, gRawF, 64,
              nullptr, 0, S_, 64, 1536, 5);
        sigcoef_kernel<<<S_ * SLn / 256, 256, 0, stream>>>(gRawF, coefF, gaF, gbF);
        scan_part_kernel<<<256, 256, 0, stream>>>(itemsF, gaF, gbF, pF, pS);
        scan_reduce_kernel<<<64, 256, 0, stream>>>(
            pF, pS, coefF, fast0, slow0, outP + LOGITS_N + (size_t)l * SLn * D_,
            outP + LOGITS_N + (size_t)Lc * SLn * D_ + (size_t)l * SLn * D_);
        gemmM(stream, qrB, 1536, wOutT + (size_t)l * H_ * 1536, b_out + l * H_, outF, H_,
              nullptr, 0, S_, H_, 1536, 5);
        ln_kernel<<<S_, 256, 0, stream>>>(hF, outF, ln1_g + l * H_, ln1_b + l * H_, hF, hB, 1536);
        gemmM(stream, hB, 1536, f1T + (size_t)l * I_ * H_, ffn_b1 + l * I_, nullptr, 0, ffn1B,
              I_, S_, I_, H_, 11);
        gemmM(stream, ffn1B, I_, f2T + (size_t)l * H_ * I_, ffn_b2 + l * H_, outF, H_, nullptr,
              0, S_, H_, I_, 5);
        ln_kernel<<<S_, 256, 0, stream>>>(hF, outF, ln2_g + l * H_, ln2_b + l * H_, hF, hB, 1536);
    }
    ln_kernel<<<S_, 256, 0, stream>>>(hF, nullptr, fln_g, fln_b, nullptr, hB, 1536);
    // logits: 256x128 tile, 4 waves, 72KB LDS -> 2 blocks/CU; grid 8x250=2000
    gemm_p6<256, 128, 256, 2, 2, 2, 4><<<2000, 256, 0, stream>>>(hB, 1536, embB, nullptr, outP,
                                                                 V_, nullptr, 0, H_, 8, 250);
}